// Round 1
// baseline (365.495 us; speedup 1.0000x reference)
//
#include <hip/hip_runtime.h>
#include <stdint.h>

// BoltzmannGateSTE: out = x * (|x| >= T) where T = k-th largest |x|, k = int(n/e).
// Exact radix-select on the abs bit pattern (monotone for non-negative floats):
//   pass A : 12-bit histogram of bits[30:19]   (privatized LDS -> per-block global -> reduce)
//   sel  A : descending scan of 4096 bins -> 12-bit prefix + remaining rank
//   pass B : 19-bit fine histogram (512K global bins, sparse atomics) + 512-bin coarse
//   sel  B : coarse scan -> 1024-bin window scan -> exact 31-bit threshold pattern
//   mask   : stream x -> out with unsigned-compare threshold.
// All selection logic is device-side (graph capture forbids host readback).

#define SEL_T 1024

constexpr int H_BLOCKS = 512;
constexpr int H_THREADS = 1024;
constexpr int NBIN1   = 4096;      // bits [30:19]
constexpr int NFINE   = 1 << 19;   // bits [18:0]
constexpr int NCOARSE = 512;       // fine >> 10

// ---------------- pass A: coarse histogram, privatized per block ----------------
__global__ __launch_bounds__(H_THREADS)
void hist_pass1(const uint4* __restrict__ x, long long n4, unsigned* __restrict__ hists)
{
    __shared__ unsigned h[NBIN1];
    for (int i = threadIdx.x; i < NBIN1; i += H_THREADS) h[i] = 0u;
    __syncthreads();
    long long stride = (long long)gridDim.x * H_THREADS;
    for (long long i = (long long)blockIdx.x * H_THREADS + threadIdx.x; i < n4; i += stride) {
        uint4 v = x[i];
        atomicAdd(&h[(v.x & 0x7FFFFFFFu) >> 19], 1u);
        atomicAdd(&h[(v.y & 0x7FFFFFFFu) >> 19], 1u);
        atomicAdd(&h[(v.z & 0x7FFFFFFFu) >> 19], 1u);
        atomicAdd(&h[(v.w & 0x7FFFFFFFu) >> 19], 1u);
    }
    __syncthreads();
    unsigned* out = hists + (size_t)blockIdx.x * NBIN1;
    for (int i = threadIdx.x; i < NBIN1; i += H_THREADS) out[i] = h[i];
}

__global__ void hist_reduce(const unsigned* __restrict__ hists, unsigned* __restrict__ histA,
                            int nblocks)
{
    int bin = blockIdx.x * blockDim.x + threadIdx.x;
    if (bin >= NBIN1) return;
    unsigned s = 0;
    for (int b = 0; b < nblocks; ++b) s += hists[(size_t)b * NBIN1 + bin];
    histA[bin] = s;
}

// ---------------- descending block select over a histogram ----------------
// Finds bin b with  sum_{j>b} hist[j] < k <= sum_{j>=b} hist[j].
// s_res[0] = b, s_res[1] = k - sum_{j>b} hist[j]  (remaining rank inside bin b).
// Must be called by all SEL_T threads; k uniform. Syncs internally before return.
__device__ void select_desc(const unsigned* __restrict__ hist, int nbins,
                            unsigned k, unsigned* s_scan, int* s_res)
{
    int tid = threadIdx.x;
    if (tid == 0) { s_res[0] = -1; s_res[1] = 0; }
    __syncthreads();
    unsigned running = 0;
    for (int top = nbins; top > 0; top -= SEL_T) {
        int bin = top - 1 - tid;                      // j=tid counts down from chunk top
        unsigned v = (bin >= 0) ? hist[bin] : 0u;
        s_scan[tid] = v;
        __syncthreads();
        // inclusive Hillis-Steele prefix scan in j-order == suffix sums in bin-order
        for (int off = 1; off < SEL_T; off <<= 1) {
            unsigned add = (tid >= off) ? s_scan[tid - off] : 0u;
            __syncthreads();
            s_scan[tid] += add;
            __syncthreads();
        }
        unsigned p     = s_scan[tid];
        unsigned pprev = (tid > 0) ? s_scan[tid - 1] : 0u;
        unsigned total = s_scan[SEL_T - 1];
        __syncthreads();
        if (running + total >= k) {
            if (bin >= 0 && running + p >= k && running + pprev < k) {
                s_res[0] = bin;
                s_res[1] = (int)(k - running - pprev);
            }
            __syncthreads();
            return;
        }
        running += total;
    }
    // unreachable unless k exceeds the grand total; fail safe to lowest bin
    if (tid == 0 && s_res[0] < 0) { s_res[0] = 0; s_res[1] = 1; }
    __syncthreads();
}

__global__ __launch_bounds__(SEL_T)
void select1_kernel(const unsigned* __restrict__ histA, unsigned* __restrict__ state, unsigned k)
{
    __shared__ unsigned s_scan[SEL_T];
    __shared__ int s_res[2];
    select_desc(histA, NBIN1, k, s_scan, s_res);
    if (threadIdx.x == 0) { state[0] = (unsigned)s_res[0]; state[1] = (unsigned)s_res[1]; }
}

// ---------------- pass B: fine histogram among prefix-matching elements ----------------
__global__ __launch_bounds__(H_THREADS)
void hist_pass2(const uint4* __restrict__ x, long long n4, const unsigned* __restrict__ state,
                unsigned* __restrict__ fineB, unsigned* __restrict__ coarseB)
{
    __shared__ unsigned hc[NCOARSE];
    for (int i = threadIdx.x; i < NCOARSE; i += H_THREADS) hc[i] = 0u;
    __syncthreads();
    unsigned pref = state[0];
    long long stride = (long long)gridDim.x * H_THREADS;
    for (long long i = (long long)blockIdx.x * H_THREADS + threadIdx.x; i < n4; i += stride) {
        uint4 v = x[i];
        unsigned u;
        u = v.x & 0x7FFFFFFFu;
        if ((u >> 19) == pref) { atomicAdd(&fineB[u & (NFINE - 1)], 1u); atomicAdd(&hc[(u & (NFINE - 1)) >> 10], 1u); }
        u = v.y & 0x7FFFFFFFu;
        if ((u >> 19) == pref) { atomicAdd(&fineB[u & (NFINE - 1)], 1u); atomicAdd(&hc[(u & (NFINE - 1)) >> 10], 1u); }
        u = v.z & 0x7FFFFFFFu;
        if ((u >> 19) == pref) { atomicAdd(&fineB[u & (NFINE - 1)], 1u); atomicAdd(&hc[(u & (NFINE - 1)) >> 10], 1u); }
        u = v.w & 0x7FFFFFFFu;
        if ((u >> 19) == pref) { atomicAdd(&fineB[u & (NFINE - 1)], 1u); atomicAdd(&hc[(u & (NFINE - 1)) >> 10], 1u); }
    }
    __syncthreads();
    for (int i = threadIdx.x; i < NCOARSE; i += H_THREADS)
        if (hc[i]) atomicAdd(&coarseB[i], hc[i]);
}

__global__ __launch_bounds__(SEL_T)
void select2_kernel(const unsigned* __restrict__ fineB, const unsigned* __restrict__ coarseB,
                    unsigned* __restrict__ state)
{
    __shared__ unsigned s_scan[SEL_T];
    __shared__ int s_res[2];
    unsigned pref = state[0];
    unsigned k    = state[1];
    select_desc(coarseB, NCOARSE, k, s_scan, s_res);
    int c       = s_res[0];
    unsigned k1 = (unsigned)s_res[1];
    __syncthreads();
    select_desc(fineB + (size_t)c * 1024, 1024, k1, s_scan, s_res);
    int f = s_res[0];
    if (threadIdx.x == 0)
        state[2] = (pref << 19) | ((unsigned)c << 10) | (unsigned)f;  // exact 31-bit threshold
}

// ---------------- mask pass ----------------
__global__ __launch_bounds__(256)
void mask_kernel(const uint4* __restrict__ x, uint4* __restrict__ out, long long n4,
                 const unsigned* __restrict__ state)
{
    unsigned t = state[2];
    long long stride = (long long)gridDim.x * 256;
    for (long long i = (long long)blockIdx.x * 256 + threadIdx.x; i < n4; i += stride) {
        uint4 v = x[i];
        uint4 r;
        r.x = ((v.x & 0x7FFFFFFFu) >= t) ? v.x : 0u;
        r.y = ((v.y & 0x7FFFFFFFu) >= t) ? v.y : 0u;
        r.z = ((v.z & 0x7FFFFFFFu) >= t) ? v.z : 0u;
        r.w = ((v.w & 0x7FFFFFFFu) >= t) ? v.w : 0u;
        out[i] = r;
    }
}

extern "C" void kernel_launch(void* const* d_in, const int* in_sizes, int n_in,
                              void* d_out, int out_size, void* d_ws, size_t ws_size,
                              hipStream_t stream)
{
    long long n  = (long long)in_sizes[0];
    if (n <= 0) return;
    long long n4 = n >> 2;   // n = 4*4096*2048, divisible by 4

    // k = max(1, int(n * (1/e))) — identical IEEE double arithmetic to the Python ref
    const double FRACTION = 1.0 / 2.718281828459045;
    long long k = (long long)((double)n * FRACTION);
    if (k < 1) k = 1;
    // (k >= n would degenerate to threshold = min |x| -> keep-all, which is correct)

    // workspace layout
    size_t off_hists  = 0;
    size_t off_histA  = off_hists  + (size_t)H_BLOCKS * NBIN1 * 4;
    size_t off_fineB  = off_histA  + (size_t)NBIN1 * 4;
    size_t off_coarse = off_fineB  + (size_t)NFINE * 4;
    size_t off_state  = off_coarse + (size_t)NCOARSE * 4;
    size_t need       = off_state + 64;

    uint8_t* base;
    unsigned* state;
    if (ws_size >= need) {
        base  = (uint8_t*)d_ws;
        state = (unsigned*)(base + off_state);
    } else {
        // fall back: stage histograms inside d_out (mask pass rewrites every element
        // afterwards); only the 16-byte state must live outside d_out.
        base  = (uint8_t*)d_out;
        state = (unsigned*)d_ws;
    }
    unsigned* hists   = (unsigned*)(base + off_hists);
    unsigned* histA   = (unsigned*)(base + off_histA);
    unsigned* fineB   = (unsigned*)(base + off_fineB);
    unsigned* coarseB = (unsigned*)(base + off_coarse);

    // ws/out are re-poisoned to 0xAA before every timed launch — zero what we read-modify
    hipMemsetAsync(fineB, 0, ((size_t)NFINE + NCOARSE) * 4, stream);
    hipMemsetAsync(state, 0, 16, stream);

    const uint4* x = (const uint4*)d_in[0];

    hist_pass1 <<<H_BLOCKS, H_THREADS, 0, stream>>>(x, n4, hists);
    hist_reduce<<<(NBIN1 + 255) / 256, 256, 0, stream>>>(hists, histA, H_BLOCKS);
    select1_kernel<<<1, SEL_T, 0, stream>>>(histA, state, (unsigned)k);
    hist_pass2 <<<H_BLOCKS, H_THREADS, 0, stream>>>(x, n4, state, fineB, coarseB);
    select2_kernel<<<1, SEL_T, 0, stream>>>(fineB, coarseB, state);
    mask_kernel<<<2048, 256, 0, stream>>>(x, (uint4*)d_out, n4, state);
}